// Round 10
// baseline (270.238 us; speedup 1.0000x reference)
//
#include <hip/hip_runtime.h>
#include <hip/hip_bf16.h>
#include <cstdint>
#include <cstddef>

// ThermodynamicAttention: q=xWq+bq, k=xWk+bk, v=xWv+bv (B=4,S=2048,D=1024)
// scores = q@k^T / 8 / temp; probs = softmax(scores); H = mean row entropy
// out0 = probs@v (fp32, 8388608 elems), out1 = H (1 elem)
//
// R18: R17 minus the spill. R17's launch_bounds(512,4) capped VGPR at 64 =
// exactly the acc footprint -> scratch spill (counters: VGPR_Count=64,
// FETCH +27MB, WRITE +14MB = ~40MB scratch round-trip, dur 69->74us).
// Fix: plain launch_bounds(512) on both bigm kernels; compiler's natural
// ~96-110 VGPR, no spill, still 4+ waves/SIMD at 48KB LDS. Structure
// otherwise byte-identical to R17 (which passed correctness).
//   qkv_bigm:  256x128 tile, grid 768, staged 576 MB (-25% vs 128^2)
//   scores_bigm: 256x128 tile, grid 512, staged 384 MB (R16-validated, -9us)
// pv/prep/stats_reduce/reduce_entropy unchanged (round-0 verified forms).
//
// Workspace layout (bytes), ~104 MB:
//   0          qb    (bf16, 16MB)  [q pre-scaled by 1/(8*temp)]
//   16777216   kb    (bf16, 16MB)
//   33554432   vt    (bf16 v transposed [b][d][s], 16MB)
//   50331648   xb    (bf16 x, 16MB)
//   67108864   Wt    (bf16 [Wqt|Wkt|Wvt], 6MB)
//   73400320   Pt    (bf16 e^x, 4x2048x2048, 32MB)
//   106954752  stats (fp32 [8192][32][2], 2MB)
//   109051904  inv_l (fp32 [8192], 32KB)
//   109084672  Hrow  (fp32 [8192], 32KB)

typedef __attribute__((ext_vector_type(8))) short short8;
typedef __attribute__((ext_vector_type(4))) short short4v;
typedef __attribute__((ext_vector_type(4))) float f32x4;

#define GLOBAL_AS __attribute__((address_space(1)))
#define LDS_AS __attribute__((address_space(3)))

__device__ __forceinline__ void async_load16(const void* g, void* lds) {
  __builtin_amdgcn_global_load_lds((GLOBAL_AS void*)g, (LDS_AS void*)lds, 16, 0, 0);
}

__device__ __forceinline__ short f2bf_s(float x) {
  __hip_bfloat16 h = __float2bfloat16(x);
  return *reinterpret_cast<short*>(&h);
}

// ===========================================================================
// Shared 256x128 "bigm" GEMM body: C[256,128] = A[256,K=1024] @ Bt[128,K]^T.
// 512 threads = 8 waves (wm in {0,64,128,192}, wn in {0,64}); per wave the
// round-0 verified 4x4 fragment/MFMA/swizzle code. LDS: sA 256x64 (32KB,
// 4 staging passes), sB 128x64 (16KB, 2 passes). Chunk (row,g) at
// row*8 + (g ^ (row&7)); staging thread t pass p owns chunk t+512p -> row
// (t>>3)+64p (row&7 pass-invariant), src col ((t&7)^((t>>3)&7))*8. Read
// col-group kk*4+quad at ((kk*4+quad)^(rc&7)) -> 0 bank conflicts (measured).
// MODE 1: bf16 C + bias, scaled by 1/(8*aux[0]) if aux (q) else 1 (k)
// MODE 2: bf16 transposed-v + bias   (vt[b][col][s], b=row>>11)
// MODE 3: P~ = bf16(e^acc) + per-(row,chunk64) stats (l = sum e, w = sum e*x)
// ===========================================================================
template <int MODE>
__device__ __forceinline__
void gemm_bigm(const __hip_bfloat16* __restrict__ A,
               const __hip_bfloat16* __restrict__ Bt,
               void* __restrict__ Cout,
               const float* __restrict__ bias, int ldc,
               __hip_bfloat16* __restrict__ sA,
               __hip_bfloat16* __restrict__ sB,
               int m0, int n0,
               const float* __restrict__ aux,
               float* __restrict__ stats) {
  const int tid  = threadIdx.x;
  const int lane = tid & 63;
  const int wid  = tid >> 6;           // 0..7
  const int wm   = (wid >> 1) * 64;    // 0,64,128,192
  const int wn   = (wid & 1) * 64;     // 0,64
  const int quad = lane >> 4;
  const int rc   = lane & 15;

  f32x4 acc[4][4] = {};

  const int srow = tid >> 3;                          // 0..63
  const int scol = ((tid & 7) ^ ((tid >> 3) & 7)) * 8;
  const __hip_bfloat16* Ag = A  + (size_t)(m0 + srow) * 1024 + scol;
  const __hip_bfloat16* Bg = Bt + (size_t)(n0 + srow) * 1024 + scol;

  for (int k0 = 0; k0 < 1024; k0 += 64) {
#pragma unroll
    for (int p = 0; p < 4; ++p)
      async_load16(Ag + k0 + (size_t)(64 * p) * 1024, &sA[(tid + 512 * p) * 8]);
#pragma unroll
    for (int p = 0; p < 2; ++p)
      async_load16(Bg + k0 + (size_t)(64 * p) * 1024, &sB[(tid + 512 * p) * 8]);
    __syncthreads();

#pragma unroll
    for (int kk = 0; kk < 2; ++kk) {
      const int xo = ((kk * 4 + quad) ^ (rc & 7)) * 8;
      short8 af[4], bf[4];
#pragma unroll
      for (int i = 0; i < 4; ++i)
        af[i] = *(const short8*)&sA[(wm + i * 16 + rc) * 64 + xo];
#pragma unroll
      for (int i = 0; i < 4; ++i)
        bf[i] = *(const short8*)&sB[(wn + i * 16 + rc) * 64 + xo];

#pragma unroll
      for (int mi = 0; mi < 4; ++mi)
#pragma unroll
        for (int ni = 0; ni < 4; ++ni)
          acc[mi][ni] = __builtin_amdgcn_mfma_f32_16x16x32_bf16(
              af[mi], bf[ni], acc[mi][ni], 0, 0, 0);
    }
    __syncthreads();
  }

  // Epilogues. C/D layout (m89-verified): row = quad*4 + reg, col = lane&15.
  if (MODE == 3) {
    const int chunk = (n0 + wn) >> 6;
#pragma unroll
    for (int mi = 0; mi < 4; ++mi) {
      float l_acc[4] = {}, w_acc[4] = {};
#pragma unroll
      for (int ni = 0; ni < 4; ++ni)
#pragma unroll
        for (int r = 0; r < 4; ++r) {
          const float xv = acc[mi][ni][r];   // already /(8*temp): q pre-scaled
          const float e = __expf(xv);
          acc[mi][ni][r] = e;
          l_acc[r] += e;
          w_acc[r] += e * xv;
        }
#pragma unroll
      for (int r = 0; r < 4; ++r) {
        float l = l_acc[r], w = w_acc[r];
#pragma unroll
        for (int off = 1; off < 16; off <<= 1) {
          l += __shfl_xor(l, off);
          w += __shfl_xor(w, off);
        }
        if (rc == 0) {
          const int row = m0 + wm + mi * 16 + quad * 4 + r;
          *(float2*)&stats[((size_t)row * 32 + chunk) * 2] = make_float2(l, w);
        }
      }
#pragma unroll
      for (int ni = 0; ni < 4; ++ni) {
        const int col = n0 + wn + ni * 16 + rc;
#pragma unroll
        for (int r = 0; r < 4; ++r) {
          const int row = m0 + wm + mi * 16 + quad * 4 + r;
          ((__hip_bfloat16*)Cout)[(size_t)row * ldc + col] =
              __float2bfloat16(acc[mi][ni][r]);
        }
      }
    }
  } else {
    const float qsc = (MODE == 1 && aux) ? 1.0f / (8.0f * aux[0]) : 1.0f;
#pragma unroll
    for (int mi = 0; mi < 4; ++mi) {
#pragma unroll
      for (int ni = 0; ni < 4; ++ni) {
        const int col = n0 + wn + ni * 16 + rc;
        const float badd = bias[col];
        if (MODE == 2) {
          const int rowb = m0 + wm + mi * 16 + quad * 4;
          short4v o;
#pragma unroll
          for (int r = 0; r < 4; ++r) o[r] = f2bf_s(acc[mi][ni][r] + badd);
          const size_t idx = (size_t)(rowb >> 11) * (1024u * 2048u) +
                             (size_t)col * 2048u + (size_t)(rowb & 2047);
          *(short4v*)((short*)Cout + idx) = o;
        } else {
#pragma unroll
          for (int r = 0; r < 4; ++r) {
            const int row = m0 + wm + mi * 16 + quad * 4 + r;
            ((__hip_bfloat16*)Cout)[(size_t)row * ldc + col] =
                __float2bfloat16((acc[mi][ni][r] + badd) * qsc);
          }
        }
      }
    }
  }
}

// QKV: grid 768 (32 mt x 24 nt), chunked XCD swizzle (768 = 8*96).
// Consecutive G share the A strip (same mt) -> L2-hot within an XCD chunk.
__global__ __launch_bounds__(512)
void qkv_bigm(const __hip_bfloat16* __restrict__ xb,
              const __hip_bfloat16* __restrict__ Wt,
              __hip_bfloat16* __restrict__ qb, __hip_bfloat16* __restrict__ kb,
              __hip_bfloat16* __restrict__ vt,
              const float* __restrict__ bq, const float* __restrict__ bk,
              const float* __restrict__ bv, const float* __restrict__ tptr) {
  __shared__ __align__(16) __hip_bfloat16 sA[256 * 64];  // 32 KB
  __shared__ __align__(16) __hip_bfloat16 sB[128 * 64];  // 16 KB
  const int lin = blockIdx.x;
  const int G = (lin & 7) * 96 + (lin >> 3);   // bijective: 768 = 8 * 96
  const int mt = G / 24;                       // 0..31 (256-row tiles)
  const int r  = G % 24;
  const int z  = r >> 3;                       // 0..2 (q/k/v)
  const int x  = r & 7;                        // 0..7 (128-col tiles)
  const int m0 = mt * 256, n0 = x * 128;
  const __hip_bfloat16* B = Wt + (size_t)z * 1024 * 1024;
  if (z == 0)
    gemm_bigm<1>(xb, B, qb, bq, 1024, sA, sB, m0, n0, tptr, nullptr);
  else if (z == 1)
    gemm_bigm<1>(xb, B, kb, bk, 1024, sA, sB, m0, n0, nullptr, nullptr);
  else
    gemm_bigm<2>(xb, B, vt, bv, 0, sA, sB, m0, n0, nullptr, nullptr);
}

// Scores->P~: grid 512 (4 z x 8 y x 16 x), chunked XCD swizzle (512 = 8*64).
__global__ __launch_bounds__(512)
void scores_bigm(const __hip_bfloat16* __restrict__ qb,
                 const __hip_bfloat16* __restrict__ kb,
                 __hip_bfloat16* __restrict__ Pt,
                 float* __restrict__ stats) {
  __shared__ __align__(16) __hip_bfloat16 sA[256 * 64];  // 32 KB
  __shared__ __align__(16) __hip_bfloat16 sB[128 * 64];  // 16 KB
  const int lin = blockIdx.x;
  const int G = (lin & 7) * 64 + (lin >> 3);   // bijective: 512 = 8 * 64
  const size_t z = G >> 7;                     // batch (128 tiles each)
  const int rr = G & 127;
  const int y = rr >> 4;                       // 0..7  (256-row tiles)
  const int x = rr & 15;                       // 0..15 (128-col tiles)
  gemm_bigm<3>(qb + z * 2048 * 1024, kb + z * 2048 * 1024,
               Pt + z * 2048 * 2048, nullptr, 2048,
               sA, sB, y * 256, x * 128, nullptr, stats + z * 2048 * 64);
}

// ---------------------------------------------------------------------------
// PV: round-0 verified 128^2 body (512 blocks -> 2/CU).
// ---------------------------------------------------------------------------
__device__ __forceinline__
void gemm_pv(const __hip_bfloat16* __restrict__ A,
             const __hip_bfloat16* __restrict__ Bt,
             float* __restrict__ Cout,
             int K, int lda, int ldb, int ldc,
             __hip_bfloat16* __restrict__ sA,
             __hip_bfloat16* __restrict__ sB,
             int m0, int n0,
             const float* __restrict__ aux) {
  const int tid  = threadIdx.x;
  const int lane = tid & 63;
  const int wid  = tid >> 6;
  const int wm = (wid >> 1) * 64;
  const int wn = (wid & 1) * 64;
  const int quad = lane >> 4;
  const int rc   = lane & 15;

  f32x4 acc[4][4] = {};

  const int srow = tid >> 3;
  const int scol = ((tid & 7) ^ ((tid >> 3) & 7)) * 8;
  const __hip_bfloat16* Ag = A  + (size_t)(m0 + srow) * lda + scol;
  const __hip_bfloat16* Bg = Bt + (size_t)(n0 + srow) * ldb + scol;

  for (int k0 = 0; k0 < K; k0 += 64) {
#pragma unroll
    for (int p = 0; p < 4; ++p) {
      async_load16(Ag + k0 + (size_t)(32 * p) * lda, &sA[(wid * 64 + 256 * p) * 8]);
      async_load16(Bg + k0 + (size_t)(32 * p) * ldb, &sB[(wid * 64 + 256 * p) * 8]);
    }
    __syncthreads();

#pragma unroll
    for (int kk = 0; kk < 2; ++kk) {
      const int xo = ((kk * 4 + quad) ^ (rc & 7)) * 8;
      short8 af[4], bf[4];
#pragma unroll
      for (int i = 0; i < 4; ++i)
        af[i] = *(const short8*)&sA[(wm + i * 16 + rc) * 64 + xo];
#pragma unroll
      for (int i = 0; i < 4; ++i)
        bf[i] = *(const short8*)&sB[(wn + i * 16 + rc) * 64 + xo];

#pragma unroll
      for (int mi = 0; mi < 4; ++mi)
#pragma unroll
        for (int ni = 0; ni < 4; ++ni)
          acc[mi][ni] = __builtin_amdgcn_mfma_f32_16x16x32_bf16(
              af[mi], bf[ni], acc[mi][ni], 0, 0, 0);
    }
    __syncthreads();
  }

#pragma unroll
  for (int mi = 0; mi < 4; ++mi) {
    float sc[4];
#pragma unroll
    for (int r = 0; r < 4; ++r)
      sc[r] = aux[m0 + wm + mi * 16 + quad * 4 + r];
#pragma unroll
    for (int ni = 0; ni < 4; ++ni) {
      const int col = n0 + wn + ni * 16 + rc;
#pragma unroll
      for (int r = 0; r < 4; ++r) {
        const int row = m0 + wm + mi * 16 + quad * 4 + r;
        Cout[(size_t)row * ldc + col] = acc[mi][ni][r] * sc[r];
      }
    }
  }
}

// PV: flat grid 512. Group = 4 blocks (2y x 2x). out scaled by inv_l[row].
__global__ __launch_bounds__(256)
void pv_swz(const __hip_bfloat16* __restrict__ Pt,
            const __hip_bfloat16* __restrict__ vt,
            float* __restrict__ out,
            const float* __restrict__ inv_l) {
  __shared__ __align__(16) __hip_bfloat16 sA[128 * 64];
  __shared__ __align__(16) __hip_bfloat16 sB[128 * 64];
  const int lin = blockIdx.x;
  const int j = lin & 7, t = lin >> 3;
  const int w = t & 3;
  const int G = j + 8 * (t >> 2);
  const size_t z = G >> 5;
  const int r = G & 31;
  const int y = (r >> 2) * 2 + (w >> 1);
  const int x = (r & 3) * 2 + (w & 1);
  gemm_pv(Pt + z * 2048 * 2048, vt + z * 1024 * 2048,
          out + z * 2048 * 1024, 2048, 2048, 2048, 1024,
          sA, sB, y * 128, x * 128, inv_l + z * 2048);
}

// ---------------------------------------------------------------------------
// Fused prep: blocks [0,4096) cast x->xb (bf16x8); blocks [4096,4864) do the
// three weight transposes (z = (b-4096)>>8, 16x16 tiles of 64x64).
__global__ __launch_bounds__(256)
void prep_fused(const float* __restrict__ x, __hip_bfloat16* __restrict__ xb,
                const float* __restrict__ Wq, const float* __restrict__ Wk,
                const float* __restrict__ Wv, __hip_bfloat16* __restrict__ Wt) {
  if (blockIdx.x < 4096) {
    const int i = (blockIdx.x * 256 + threadIdx.x) * 8;
    const float4 a = *(const float4*)(x + i);
    const float4 b = *(const float4*)(x + i + 4);
    short8 o;
    o[0] = f2bf_s(a.x); o[1] = f2bf_s(a.y); o[2] = f2bf_s(a.z); o[3] = f2bf_s(a.w);
    o[4] = f2bf_s(b.x); o[5] = f2bf_s(b.y); o[6] = f2bf_s(b.z); o[7] = f2bf_s(b.w);
    *(short8*)((short*)xb + i) = o;
  } else {
    __shared__ float tile[64][65];
    const int b = blockIdx.x - 4096;
    const int z = b >> 8;
    const int rem = b & 255;
    const int c0 = (rem & 15) * 64;
    const int r0 = (rem >> 4) * 64;
    const float* src = (z == 0) ? Wq : (z == 1) ? Wk : Wv;
    __hip_bfloat16* dst = Wt + (size_t)z * 1024 * 1024;
    const int lane = threadIdx.x & 63;
    const int grp  = threadIdx.x >> 6;
#pragma unroll
    for (int i = 0; i < 16; ++i) {
      const int r = grp * 16 + i;
      tile[r][lane] = src[(size_t)(r0 + r) * 1024 + c0 + lane];
    }
    __syncthreads();
#pragma unroll
    for (int i = 0; i < 16; ++i) {
      const int r = grp * 16 + i;
      dst[(size_t)(c0 + r) * 1024 + r0 + lane] = __float2bfloat16(tile[lane][r]);
    }
  }
}

// ---------------------------------------------------------------------------
// Per-row stats reduction: row's 32 (l,w) chunk-pairs (256B contiguous) ->
// inv_l[row] = 1/sum(l), Hrow[row] = log(l) - w/l. 8192 rows, 32 blocks.
__global__ __launch_bounds__(256)
void stats_reduce(const float* __restrict__ stats,
                  float* __restrict__ inv_l, float* __restrict__ Hrow) {
  const int row = blockIdx.x * 256 + threadIdx.x;
  const float* sp = stats + (size_t)row * 64;
  float l = 0.f, w = 0.f;
#pragma unroll
  for (int j = 0; j < 16; ++j) {
    const float4 a = *(const float4*)(sp + j * 4);
    l += a.x + a.z;
    w += a.y + a.w;
  }
  const float il = 1.0f / l;
  inv_l[row] = il;
  Hrow[row] = __logf(l) - w * il;
}

// One block: sum Hrow[0..8191], out = mean.
__global__ __launch_bounds__(256)
void reduce_entropy(const float* __restrict__ Hrow, float* __restrict__ out) {
  const int tid  = threadIdx.x;
  const int lane = tid & 63;
  const int wid  = tid >> 6;
  float s = 0.f;
#pragma unroll
  for (int j = 0; j < 8; ++j) {
    const float4 a = *(const float4*)(Hrow + j * 1024 + tid * 4);
    s += a.x + a.y + a.z + a.w;
  }
#pragma unroll
  for (int off = 1; off < 64; off <<= 1) s += __shfl_xor(s, off);
  __shared__ float red[4];
  if (lane == 0) red[wid] = s;
  __syncthreads();
  if (tid == 0)
    out[0] = (red[0] + red[1] + red[2] + red[3]) * (1.0f / 8192.0f);
}

// ---------------------------------------------------------------------------
extern "C" void kernel_launch(void* const* d_in, const int* in_sizes, int n_in,
                              void* d_out, int out_size, void* d_ws, size_t ws_size,
                              hipStream_t stream) {
  const float* x    = (const float*)d_in[0];
  const float* Wq   = (const float*)d_in[1];
  const float* bq   = (const float*)d_in[2];
  const float* Wk   = (const float*)d_in[3];
  const float* bk   = (const float*)d_in[4];
  const float* Wv   = (const float*)d_in[5];
  const float* bv   = (const float*)d_in[6];
  const float* temp = (const float*)d_in[7];
  float* out = (float*)d_out;
  char* ws = (char*)d_ws;

  __hip_bfloat16* qb    = (__hip_bfloat16*)(ws + 0);
  __hip_bfloat16* kb    = (__hip_bfloat16*)(ws + 16777216);
  __hip_bfloat16* vt    = (__hip_bfloat16*)(ws + 33554432);
  __hip_bfloat16* xb    = (__hip_bfloat16*)(ws + 50331648);
  __hip_bfloat16* Wt    = (__hip_bfloat16*)(ws + 67108864);
  __hip_bfloat16* Pt    = (__hip_bfloat16*)(ws + 73400320);
  float*          stats = (float*)(ws + 106954752);
  float*          inv_l = (float*)(ws + 109051904);
  float*          Hrow  = (float*)(ws + 109084672);

  prep_fused<<<4864, 256, 0, stream>>>(x, xb, Wq, Wk, Wv, Wt);

  qkv_bigm<<<768, 512, 0, stream>>>(xb, Wt, qb, kb, vt, bq, bk, bv, temp);

  scores_bigm<<<512, 512, 0, stream>>>(qb, kb, Pt, stats);
  stats_reduce<<<32, 256, 0, stream>>>(stats, inv_l, Hrow);
  pv_swz<<<512, 256, 0, stream>>>(Pt, vt, out, inv_l);

  reduce_entropy<<<1, 256, 0, stream>>>(Hrow, out + 8388608);
}

// Round 11
// 247.064 us; speedup vs baseline: 1.0938x; 1.0938x over previous
//
#include <hip/hip_runtime.h>
#include <hip/hip_bf16.h>
#include <cstdint>
#include <cstddef>

// ThermodynamicAttention: q=xWq+bq, k=xWk+bk, v=xWv+bv (B=4,S=2048,D=1024)
// scores = q@k^T / 8 / temp; probs = softmax(scores); H = mean row entropy
// out0 = probs@v (fp32, 8388608 elems), out1 = H (1 elem)
//
// R19: operand-aware tile growth. R17/R18 taught: growing a tile dimension
// only pays if it amortizes a STREAM operand; qkv_bigm halved L2-hot weight
// re-reads (cheap bytes) while costing TLP -> slower (FETCH 49->86MB).
//   - qkv: REVERTED to round-0 128^2 form (1536 blocks, 5/CU, 69us).
//   - scores: R16-validated 256x128 grow-M (halves k-stream re-reads).
//   - pv: NEW 128x256 grow-N (halves Pt-stream re-reads, the 32MB operand):
//     sA 16KB 2-pass, sB 32KB 4-pass, 8 waves 2m x 4n, grid 256 = 1/CU.
// prep/stats_reduce/reduce_entropy unchanged (round-0 verified forms).
//
// Workspace layout (bytes), ~104 MB:
//   0          qb    (bf16, 16MB)  [q pre-scaled by 1/(8*temp)]
//   16777216   kb    (bf16, 16MB)
//   33554432   vt    (bf16 v transposed [b][d][s], 16MB)
//   50331648   xb    (bf16 x, 16MB)
//   67108864   Wt    (bf16 [Wqt|Wkt|Wvt], 6MB)
//   73400320   Pt    (bf16 e^x, 4x2048x2048, 32MB)
//   106954752  stats (fp32 [8192][32][2], 2MB)
//   109051904  inv_l (fp32 [8192], 32KB)
//   109084672  Hrow  (fp32 [8192], 32KB)

typedef __attribute__((ext_vector_type(8))) short short8;
typedef __attribute__((ext_vector_type(4))) short short4v;
typedef __attribute__((ext_vector_type(4))) float f32x4;

#define GLOBAL_AS __attribute__((address_space(1)))
#define LDS_AS __attribute__((address_space(3)))

__device__ __forceinline__ void async_load16(const void* g, void* lds) {
  __builtin_amdgcn_global_load_lds((GLOBAL_AS void*)g, (LDS_AS void*)lds, 16, 0, 0);
}

__device__ __forceinline__ short f2bf_s(float x) {
  __hip_bfloat16 h = __float2bfloat16(x);
  return *reinterpret_cast<short*>(&h);
}

// ---------------------------------------------------------------------------
// bf16 "bt" GEMM body (round-0 verified): C[M,N] = A[M,K] @ Bt[N,K]^T,
// 128x128 tile, BK=64, 256 threads = 4 waves in 2x2, each wave 4x4 grid of
// 16x16x32 MFMA, 2 k-steps. LDS per operand 16KB, XOR-chunk swizzle:
// chunk (row,g) at row*8 + (g ^ (row&7)); staging thread t pass p owns chunk
// t+256p -> source row (t>>3)+32p, col ((t&7)^((t>>3)&7))*8. Read col-group
// kk*4+quad at ((kk*4+quad)^(rc&7)) -> 0 bank conflicts (measured).
// MODE 1: bf16 C + bias, scaled by 1/(8*aux[0]) if aux (q) else 1 (k)
// MODE 2: bf16 transposed-v + bias   (vt[b][col][s], b=row>>11)
// ---------------------------------------------------------------------------
template <int MODE>
__device__ __forceinline__
void gemm_body(const __hip_bfloat16* __restrict__ A,
               const __hip_bfloat16* __restrict__ Bt,
               void* __restrict__ Cout,
               const float* __restrict__ bias,
               int K, int lda, int ldb, int ldc,
               __hip_bfloat16* __restrict__ sA,
               __hip_bfloat16* __restrict__ sB,
               int m0, int n0,
               const float* __restrict__ aux) {
  const int tid  = threadIdx.x;
  const int lane = tid & 63;
  const int wid  = tid >> 6;
  const int wm = (wid >> 1) * 64;
  const int wn = (wid & 1) * 64;
  const int quad = lane >> 4;
  const int rc   = lane & 15;

  f32x4 acc[4][4] = {};

  const int srow = tid >> 3;
  const int scol = ((tid & 7) ^ ((tid >> 3) & 7)) * 8;
  const __hip_bfloat16* Ag = A  + (size_t)(m0 + srow) * lda + scol;
  const __hip_bfloat16* Bg = Bt + (size_t)(n0 + srow) * ldb + scol;

  for (int k0 = 0; k0 < K; k0 += 64) {
#pragma unroll
    for (int p = 0; p < 4; ++p) {
      async_load16(Ag + k0 + (size_t)(32 * p) * lda, &sA[(wid * 64 + 256 * p) * 8]);
      async_load16(Bg + k0 + (size_t)(32 * p) * ldb, &sB[(wid * 64 + 256 * p) * 8]);
    }
    __syncthreads();

#pragma unroll
    for (int kk = 0; kk < 2; ++kk) {
      const int xo = ((kk * 4 + quad) ^ (rc & 7)) * 8;
      short8 af[4], bf[4];
#pragma unroll
      for (int i = 0; i < 4; ++i)
        af[i] = *(const short8*)&sA[(wm + i * 16 + rc) * 64 + xo];
#pragma unroll
      for (int i = 0; i < 4; ++i)
        bf[i] = *(const short8*)&sB[(wn + i * 16 + rc) * 64 + xo];

#pragma unroll
      for (int mi = 0; mi < 4; ++mi)
#pragma unroll
        for (int ni = 0; ni < 4; ++ni)
          acc[mi][ni] = __builtin_amdgcn_mfma_f32_16x16x32_bf16(
              af[mi], bf[ni], acc[mi][ni], 0, 0, 0);
    }
    __syncthreads();
  }

  const float qsc = (MODE == 1 && aux) ? 1.0f / (8.0f * aux[0]) : 1.0f;
#pragma unroll
  for (int mi = 0; mi < 4; ++mi) {
#pragma unroll
    for (int ni = 0; ni < 4; ++ni) {
      const int col = n0 + wn + ni * 16 + rc;
      const float badd = bias[col];
      if (MODE == 2) {
        const int rowb = m0 + wm + mi * 16 + quad * 4;
        short4v o;
#pragma unroll
        for (int r = 0; r < 4; ++r) o[r] = f2bf_s(acc[mi][ni][r] + badd);
        const size_t idx = (size_t)(rowb >> 11) * (1024u * 2048u) +
                           (size_t)col * 2048u + (size_t)(rowb & 2047);
        *(short4v*)((short*)Cout + idx) = o;
      } else {
#pragma unroll
        for (int r = 0; r < 4; ++r) {
          const int row = m0 + wm + mi * 16 + quad * 4 + r;
          ((__hip_bfloat16*)Cout)[(size_t)row * ldc + col] =
              __float2bfloat16((acc[mi][ni][r] + badd) * qsc);
        }
      }
    }
  }
}

// QKV: flat grid 1536. Group = 8 blocks (fixed y, all 8 x) sharing one A-strip.
__global__ __launch_bounds__(256)
void qkv_fused(const __hip_bfloat16* __restrict__ xb,
               const __hip_bfloat16* __restrict__ Wt,
               __hip_bfloat16* __restrict__ qb, __hip_bfloat16* __restrict__ kb,
               __hip_bfloat16* __restrict__ vt,
               const float* __restrict__ bq, const float* __restrict__ bk,
               const float* __restrict__ bv, const float* __restrict__ tptr) {
  __shared__ __align__(16) __hip_bfloat16 sA[128 * 64];
  __shared__ __align__(16) __hip_bfloat16 sB[128 * 64];
  const int lin = blockIdx.x;
  const int j = lin & 7, t = lin >> 3;
  const int x = t & 7;
  const int G = j + 8 * (t >> 3);
  const int z = G >> 6, y = G & 63;
  const int m0 = y * 128, n0 = x * 128;

  const __hip_bfloat16* B = Wt + (size_t)z * 1024 * 1024;
  if (z == 0)
    gemm_body<1>(xb, B, qb, bq, 1024, 1024, 1024, 1024, sA, sB, m0, n0, tptr);
  else if (z == 1)
    gemm_body<1>(xb, B, kb, bk, 1024, 1024, 1024, 1024, sA, sB, m0, n0, nullptr);
  else
    gemm_body<2>(xb, B, vt, bv, 1024, 1024, 1024, 0, sA, sB, m0, n0, nullptr);
}

// ---------------------------------------------------------------------------
// Scores->P~: 256x128 tile, 512 threads (8 waves, 4m x 2n), BK=64.
// R16-validated: staged 384 MB (-25% vs 128^2 grid 1024), LDS 48KB -> 2/CU.
// MODE-3 epilogue: P~ = bf16(e^acc) + per-(row,chunk64) stats (l,w).
// ---------------------------------------------------------------------------
__global__ __launch_bounds__(512)
void scores_bigm(const __hip_bfloat16* __restrict__ qb,
                 const __hip_bfloat16* __restrict__ kb,
                 __hip_bfloat16* __restrict__ Pt,
                 float* __restrict__ stats) {
  __shared__ __align__(16) __hip_bfloat16 sA[256 * 64];  // 32 KB
  __shared__ __align__(16) __hip_bfloat16 sB[128 * 64];  // 16 KB
  const int lin = blockIdx.x;
  const int G = (lin & 7) * 64 + (lin >> 3);   // bijective: 512 = 8 * 64
  const size_t z = G >> 7;                     // batch (128 tiles each)
  const int rr = G & 127;
  const int y = rr >> 4;                       // 0..7  (256-row tiles)
  const int x = rr & 15;                       // 0..15 (128-col tiles)
  const int m0 = y * 256, n0 = x * 128;
  const __hip_bfloat16* A  = qb + z * 2048 * 1024;
  const __hip_bfloat16* Bt = kb + z * 2048 * 1024;
  __hip_bfloat16* Cout = Pt + z * 2048 * 2048;
  float* st = stats + z * 2048 * 64;

  const int tid  = threadIdx.x;
  const int lane = tid & 63;
  const int wid  = tid >> 6;           // 0..7
  const int wm   = (wid >> 1) * 64;    // 0,64,128,192
  const int wn   = (wid & 1) * 64;     // 0,64
  const int quad = lane >> 4;
  const int rc   = lane & 15;

  f32x4 acc[4][4] = {};

  const int srow = tid >> 3;                          // 0..63
  const int scol = ((tid & 7) ^ ((tid >> 3) & 7)) * 8;
  const __hip_bfloat16* Ag = A  + (size_t)(m0 + srow) * 1024 + scol;
  const __hip_bfloat16* Bg = Bt + (size_t)(n0 + srow) * 1024 + scol;

  for (int k0 = 0; k0 < 1024; k0 += 64) {
#pragma unroll
    for (int p = 0; p < 4; ++p)
      async_load16(Ag + k0 + (size_t)(64 * p) * 1024, &sA[(tid + 512 * p) * 8]);
#pragma unroll
    for (int p = 0; p < 2; ++p)
      async_load16(Bg + k0 + (size_t)(64 * p) * 1024, &sB[(tid + 512 * p) * 8]);
    __syncthreads();

#pragma unroll
    for (int kk = 0; kk < 2; ++kk) {
      const int xo = ((kk * 4 + quad) ^ (rc & 7)) * 8;
      short8 af[4], bf[4];
#pragma unroll
      for (int i = 0; i < 4; ++i)
        af[i] = *(const short8*)&sA[(wm + i * 16 + rc) * 64 + xo];
#pragma unroll
      for (int i = 0; i < 4; ++i)
        bf[i] = *(const short8*)&sB[(wn + i * 16 + rc) * 64 + xo];

#pragma unroll
      for (int mi = 0; mi < 4; ++mi)
#pragma unroll
        for (int ni = 0; ni < 4; ++ni)
          acc[mi][ni] = __builtin_amdgcn_mfma_f32_16x16x32_bf16(
              af[mi], bf[ni], acc[mi][ni], 0, 0, 0);
    }
    __syncthreads();
  }

  const int chunk = (n0 + wn) >> 6;
#pragma unroll
  for (int mi = 0; mi < 4; ++mi) {
    float l_acc[4] = {}, w_acc[4] = {};
#pragma unroll
    for (int ni = 0; ni < 4; ++ni)
#pragma unroll
      for (int r = 0; r < 4; ++r) {
        const float xv = acc[mi][ni][r];   // already /(8*temp): q pre-scaled
        const float e = __expf(xv);
        acc[mi][ni][r] = e;
        l_acc[r] += e;
        w_acc[r] += e * xv;
      }
#pragma unroll
    for (int r = 0; r < 4; ++r) {
      float l = l_acc[r], w = w_acc[r];
#pragma unroll
      for (int off = 1; off < 16; off <<= 1) {
        l += __shfl_xor(l, off);
        w += __shfl_xor(w, off);
      }
      if (rc == 0) {
        const int row = m0 + wm + mi * 16 + quad * 4 + r;
        *(float2*)&st[((size_t)row * 32 + chunk) * 2] = make_float2(l, w);
      }
    }
#pragma unroll
    for (int ni = 0; ni < 4; ++ni) {
      const int col = n0 + wn + ni * 16 + rc;
#pragma unroll
      for (int r = 0; r < 4; ++r) {
        const int row = m0 + wm + mi * 16 + quad * 4 + r;
        Cout[(size_t)row * 2048 + col] = __float2bfloat16(acc[mi][ni][r]);
      }
    }
  }
}

// ---------------------------------------------------------------------------
// PV: 128x256 tile (grow-N: halves Pt-stream re-reads), 512 threads
// (8 waves, 2m x 4n), BK=64. sA 128x64 (16KB, 2 passes), sB 256x64
// (32KB, 4 passes); same XOR-chunk swizzle (pass strides 512/row 64 keep
// row&7 pass-invariant). Grid 256 = 1 block/CU, no tail.
// Epilogue: fp32 out scaled by inv_l[row].
// ---------------------------------------------------------------------------
__global__ __launch_bounds__(512)
void pv_bign(const __hip_bfloat16* __restrict__ Pt,
             const __hip_bfloat16* __restrict__ vt,
             float* __restrict__ out,
             const float* __restrict__ inv_l) {
  __shared__ __align__(16) __hip_bfloat16 sA[128 * 64];  // 16 KB
  __shared__ __align__(16) __hip_bfloat16 sB[256 * 64];  // 32 KB
  const int lin = blockIdx.x;
  const int G = (lin & 7) * 32 + (lin >> 3);   // bijective: 256 = 8 * 32
  const size_t z = G >> 6;                     // batch (64 tiles each)
  const int rr = G & 63;
  const int y = rr >> 2;                       // 0..15 (128-row tiles)
  const int x = rr & 3;                        // 0..3  (256-col tiles)
  const int m0 = y * 128, n0 = x * 256;
  const __hip_bfloat16* A  = Pt + z * 2048 * 2048;
  const __hip_bfloat16* Bt = vt + z * 1024 * 2048;
  float* Cout = out + z * 2048 * 1024;
  const float* il = inv_l + z * 2048;

  const int tid  = threadIdx.x;
  const int lane = tid & 63;
  const int wid  = tid >> 6;           // 0..7
  const int wm   = (wid >> 2) * 64;    // 0,64
  const int wn   = (wid & 3) * 64;     // 0,64,128,192
  const int quad = lane >> 4;
  const int rc   = lane & 15;

  f32x4 acc[4][4] = {};

  const int srow = tid >> 3;                          // 0..63
  const int scol = ((tid & 7) ^ ((tid >> 3) & 7)) * 8;
  const __hip_bfloat16* Ag = A  + (size_t)(m0 + srow) * 2048 + scol;
  const __hip_bfloat16* Bg = Bt + (size_t)(n0 + srow) * 2048 + scol;

  for (int k0 = 0; k0 < 2048; k0 += 64) {
#pragma unroll
    for (int p = 0; p < 2; ++p)
      async_load16(Ag + k0 + (size_t)(64 * p) * 2048, &sA[(tid + 512 * p) * 8]);
#pragma unroll
    for (int p = 0; p < 4; ++p)
      async_load16(Bg + k0 + (size_t)(64 * p) * 2048, &sB[(tid + 512 * p) * 8]);
    __syncthreads();

#pragma unroll
    for (int kk = 0; kk < 2; ++kk) {
      const int xo = ((kk * 4 + quad) ^ (rc & 7)) * 8;
      short8 af[4], bf[4];
#pragma unroll
      for (int i = 0; i < 4; ++i)
        af[i] = *(const short8*)&sA[(wm + i * 16 + rc) * 64 + xo];
#pragma unroll
      for (int i = 0; i < 4; ++i)
        bf[i] = *(const short8*)&sB[(wn + i * 16 + rc) * 64 + xo];

#pragma unroll
      for (int mi = 0; mi < 4; ++mi)
#pragma unroll
        for (int ni = 0; ni < 4; ++ni)
          acc[mi][ni] = __builtin_amdgcn_mfma_f32_16x16x32_bf16(
              af[mi], bf[ni], acc[mi][ni], 0, 0, 0);
    }
    __syncthreads();
  }

#pragma unroll
  for (int mi = 0; mi < 4; ++mi) {
    float sc[4];
#pragma unroll
    for (int r = 0; r < 4; ++r)
      sc[r] = il[m0 + wm + mi * 16 + quad * 4 + r];
#pragma unroll
    for (int ni = 0; ni < 4; ++ni) {
      const int col = n0 + wn + ni * 16 + rc;
#pragma unroll
      for (int r = 0; r < 4; ++r) {
        const int row = m0 + wm + mi * 16 + quad * 4 + r;
        Cout[(size_t)row * 1024 + col] = acc[mi][ni][r] * sc[r];
      }
    }
  }
}

// ---------------------------------------------------------------------------
// Fused prep: blocks [0,4096) cast x->xb (bf16x8); blocks [4096,4864) do the
// three weight transposes (z = (b-4096)>>8, 16x16 tiles of 64x64).
__global__ __launch_bounds__(256)
void prep_fused(const float* __restrict__ x, __hip_bfloat16* __restrict__ xb,
                const float* __restrict__ Wq, const float* __restrict__ Wk,
                const float* __restrict__ Wv, __hip_bfloat16* __restrict__ Wt) {
  if (blockIdx.x < 4096) {
    const int i = (blockIdx.x * 256 + threadIdx.x) * 8;
    const float4 a = *(const float4*)(x + i);
    const float4 b = *(const float4*)(x + i + 4);
    short8 o;
    o[0] = f2bf_s(a.x); o[1] = f2bf_s(a.y); o[2] = f2bf_s(a.z); o[3] = f2bf_s(a.w);
    o[4] = f2bf_s(b.x); o[5] = f2bf_s(b.y); o[6] = f2bf_s(b.z); o[7] = f2bf_s(b.w);
    *(short8*)((short*)xb + i) = o;
  } else {
    __shared__ float tile[64][65];
    const int b = blockIdx.x - 4096;
    const int z = b >> 8;
    const int rem = b & 255;
    const int c0 = (rem & 15) * 64;
    const int r0 = (rem >> 4) * 64;
    const float* src = (z == 0) ? Wq : (z == 1) ? Wk : Wv;
    __hip_bfloat16* dst = Wt + (size_t)z * 1024 * 1024;
    const int lane = threadIdx.x & 63;
    const int grp  = threadIdx.x >> 6;
#pragma unroll
    for (int i = 0; i < 16; ++i) {
      const int r = grp * 16 + i;
      tile[r][lane] = src[(size_t)(r0 + r) * 1024 + c0 + lane];
    }
    __syncthreads();
#pragma unroll
    for (int i = 0; i < 16; ++i) {
      const int r = grp * 16 + i;
      dst[(size_t)(c0 + r) * 1024 + r0 + lane] = __float2bfloat16(tile[lane][r]);
    }
  }
}

// ---------------------------------------------------------------------------
// Per-row stats reduction: row's 32 (l,w) chunk-pairs (256B contiguous) ->
// inv_l[row] = 1/sum(l), Hrow[row] = log(l) - w/l. 8192 rows, 32 blocks.
__global__ __launch_bounds__(256)
void stats_reduce(const float* __restrict__ stats,
                  float* __restrict__ inv_l, float* __restrict__ Hrow) {
  const int row = blockIdx.x * 256 + threadIdx.x;
  const float* sp = stats + (size_t)row * 64;
  float l = 0.f, w = 0.f;
#pragma unroll
  for (int j = 0; j < 16; ++j) {
    const float4 a = *(const float4*)(sp + j * 4);
    l += a.x + a.z;
    w += a.y + a.w;
  }
  const float il = 1.0f / l;
  inv_l[row] = il;
  Hrow[row] = __logf(l) - w * il;
}

// One block: sum Hrow[0..8191], out = mean.
__global__ __launch_bounds__(256)
void reduce_entropy(const float* __restrict__ Hrow, float* __restrict__ out) {
  const int tid  = threadIdx.x;
  const int lane = tid & 63;
  const int wid  = tid >> 6;
  float s = 0.f;
#pragma unroll
  for (int j = 0; j < 8; ++j) {
    const float4 a = *(const float4*)(Hrow + j * 1024 + tid * 4);
    s += a.x + a.y + a.z + a.w;
  }
#pragma unroll
  for (int off = 1; off < 64; off <<= 1) s += __shfl_xor(s, off);
  __shared__ float red[4];
  if (lane == 0) red[wid] = s;
  __syncthreads();
  if (tid == 0)
    out[0] = (red[0] + red[1] + red[2] + red[3]) * (1.0f / 8192.0f);
}

// ---------------------------------------------------------------------------
extern "C" void kernel_launch(void* const* d_in, const int* in_sizes, int n_in,
                              void* d_out, int out_size, void* d_ws, size_t ws_size,
                              hipStream_t stream) {
  const float* x    = (const float*)d_in[0];
  const float* Wq   = (const float*)d_in[1];
  const float* bq   = (const float*)d_in[2];
  const float* Wk   = (const float*)d_in[3];
  const float* bk   = (const float*)d_in[4];
  const float* Wv   = (const float*)d_in[5];
  const float* bv   = (const float*)d_in[6];
  const float* temp = (const float*)d_in[7];
  float* out = (float*)d_out;
  char* ws = (char*)d_ws;

  __hip_bfloat16* qb    = (__hip_bfloat16*)(ws + 0);
  __hip_bfloat16* kb    = (__hip_bfloat16*)(ws + 16777216);
  __hip_bfloat16* vt    = (__hip_bfloat16*)(ws + 33554432);
  __hip_bfloat16* xb    = (__hip_bfloat16*)(ws + 50331648);
  __hip_bfloat16* Wt    = (__hip_bfloat16*)(ws + 67108864);
  __hip_bfloat16* Pt    = (__hip_bfloat16*)(ws + 73400320);
  float*          stats = (float*)(ws + 106954752);
  float*          inv_l = (float*)(ws + 109051904);
  float*          Hrow  = (float*)(ws + 109084672);

  prep_fused<<<4864, 256, 0, stream>>>(x, xb, Wq, Wk, Wv, Wt);

  qkv_fused<<<1536, 256, 0, stream>>>(xb, Wt, qb, kb, vt, bq, bk, bv, temp);

  scores_bigm<<<512, 512, 0, stream>>>(qb, kb, Pt, stats);
  stats_reduce<<<32, 256, 0, stream>>>(stats, inv_l, Hrow);
  pv_bign<<<256, 512, 0, stream>>>(Pt, vt, out, inv_l);

  reduce_entropy<<<1, 256, 0, stream>>>(Hrow, out + 8388608);
}

// Round 12
// 241.007 us; speedup vs baseline: 1.1213x; 1.0251x over previous
//
#include <hip/hip_runtime.h>
#include <hip/hip_bf16.h>
#include <cstdint>
#include <cstddef>

// ThermodynamicAttention: q=xWq+bq, k=xWk+bk, v=xWv+bv (B=4,S=2048,D=1024)
// scores = q@k^T / 8 / temp; probs = softmax(scores); H = mean row entropy
// out0 = probs@v (fp32, 8388608 elems), out1 = H (1 elem)
//
// R20: lock in the best measured configuration (R16, 243.2us). R19's pv
// grow-N (128x256, grid 256 = 1 barrier-locked block/CU) lost ~4us despite
// -25% staged traffic -> reverted per pre-committed falsifier. Session rule:
// in the 2-barrier structure, >=2 INDEPENDENT blocks/CU (phase-offset
// staging, m114 overlap) beats -25% staged bytes; grow tiles only when the
// grid keeps >=2 blocks/CU (scores_bigm 512x512t: the one winning case).
//   prep_fused:  cast + 3 weight transposes, one dispatch
//   qkv_fused:   128^2 tile, grid 1536 (5/CU), 69us, 741 TF
//   scores_bigm: 256x128 tile, grid 512 (2/CU), staged 384MB (-25%)
//   stats_reduce + pv_swz(128^2, 2/CU) + reduce_entropy
//
// Workspace layout (bytes), ~104 MB:
//   0          qb    (bf16, 16MB)  [q pre-scaled by 1/(8*temp)]
//   16777216   kb    (bf16, 16MB)
//   33554432   vt    (bf16 v transposed [b][d][s], 16MB)
//   50331648   xb    (bf16 x, 16MB)
//   67108864   Wt    (bf16 [Wqt|Wkt|Wvt], 6MB)
//   73400320   Pt    (bf16 e^x, 4x2048x2048, 32MB)
//   106954752  stats (fp32 [8192][32][2], 2MB)
//   109051904  inv_l (fp32 [8192], 32KB)
//   109084672  Hrow  (fp32 [8192], 32KB)

typedef __attribute__((ext_vector_type(8))) short short8;
typedef __attribute__((ext_vector_type(4))) short short4v;
typedef __attribute__((ext_vector_type(4))) float f32x4;

#define GLOBAL_AS __attribute__((address_space(1)))
#define LDS_AS __attribute__((address_space(3)))

__device__ __forceinline__ void async_load16(const void* g, void* lds) {
  __builtin_amdgcn_global_load_lds((GLOBAL_AS void*)g, (LDS_AS void*)lds, 16, 0, 0);
}

__device__ __forceinline__ short f2bf_s(float x) {
  __hip_bfloat16 h = __float2bfloat16(x);
  return *reinterpret_cast<short*>(&h);
}

// ---------------------------------------------------------------------------
// bf16 "bt" GEMM body (round-0 verified): C[M,N] = A[M,K] @ Bt[N,K]^T,
// 128x128 tile, BK=64, 256 threads = 4 waves in 2x2, each wave 4x4 grid of
// 16x16x32 MFMA, 2 k-steps. LDS per operand 16KB, XOR-chunk swizzle:
// chunk (row,g) at row*8 + (g ^ (row&7)); staging thread t pass p owns chunk
// t+256p -> source row (t>>3)+32p, col ((t&7)^((t>>3)&7))*8. Read col-group
// kk*4+quad at ((kk*4+quad)^(rc&7)) -> 0 bank conflicts (measured).
// MODE 1: bf16 C + bias, scaled by 1/(8*aux[0]) if aux (q) else 1 (k)
// MODE 2: bf16 transposed-v + bias   (vt[b][col][s], b=row>>11)
// MODE 4: fp32 C scaled by aux[row]  (PV normalization)
// ---------------------------------------------------------------------------
template <int MODE>
__device__ __forceinline__
void gemm_body(const __hip_bfloat16* __restrict__ A,
               const __hip_bfloat16* __restrict__ Bt,
               void* __restrict__ Cout,
               const float* __restrict__ bias,
               int K, int lda, int ldb, int ldc,
               __hip_bfloat16* __restrict__ sA,
               __hip_bfloat16* __restrict__ sB,
               int m0, int n0,
               const float* __restrict__ aux) {
  const int tid  = threadIdx.x;
  const int lane = tid & 63;
  const int wid  = tid >> 6;
  const int wm = (wid >> 1) * 64;
  const int wn = (wid & 1) * 64;
  const int quad = lane >> 4;
  const int rc   = lane & 15;

  f32x4 acc[4][4] = {};

  const int srow = tid >> 3;
  const int scol = ((tid & 7) ^ ((tid >> 3) & 7)) * 8;
  const __hip_bfloat16* Ag = A  + (size_t)(m0 + srow) * lda + scol;
  const __hip_bfloat16* Bg = Bt + (size_t)(n0 + srow) * ldb + scol;

  for (int k0 = 0; k0 < K; k0 += 64) {
#pragma unroll
    for (int p = 0; p < 4; ++p) {
      async_load16(Ag + k0 + (size_t)(32 * p) * lda, &sA[(wid * 64 + 256 * p) * 8]);
      async_load16(Bg + k0 + (size_t)(32 * p) * ldb, &sB[(wid * 64 + 256 * p) * 8]);
    }
    __syncthreads();

#pragma unroll
    for (int kk = 0; kk < 2; ++kk) {
      const int xo = ((kk * 4 + quad) ^ (rc & 7)) * 8;
      short8 af[4], bf[4];
#pragma unroll
      for (int i = 0; i < 4; ++i)
        af[i] = *(const short8*)&sA[(wm + i * 16 + rc) * 64 + xo];
#pragma unroll
      for (int i = 0; i < 4; ++i)
        bf[i] = *(const short8*)&sB[(wn + i * 16 + rc) * 64 + xo];

#pragma unroll
      for (int mi = 0; mi < 4; ++mi)
#pragma unroll
        for (int ni = 0; ni < 4; ++ni)
          acc[mi][ni] = __builtin_amdgcn_mfma_f32_16x16x32_bf16(
              af[mi], bf[ni], acc[mi][ni], 0, 0, 0);
    }
    __syncthreads();
  }

  // Epilogues. C/D layout (m89-verified): row = quad*4 + reg, col = lane&15.
  if (MODE == 4) {
#pragma unroll
    for (int mi = 0; mi < 4; ++mi) {
      float sc[4];
#pragma unroll
      for (int r = 0; r < 4; ++r)
        sc[r] = aux[m0 + wm + mi * 16 + quad * 4 + r];
#pragma unroll
      for (int ni = 0; ni < 4; ++ni) {
        const int col = n0 + wn + ni * 16 + rc;
#pragma unroll
        for (int r = 0; r < 4; ++r) {
          const int row = m0 + wm + mi * 16 + quad * 4 + r;
          ((float*)Cout)[(size_t)row * ldc + col] = acc[mi][ni][r] * sc[r];
        }
      }
    }
  } else {
    const float qsc = (MODE == 1 && aux) ? 1.0f / (8.0f * aux[0]) : 1.0f;
#pragma unroll
    for (int mi = 0; mi < 4; ++mi) {
#pragma unroll
      for (int ni = 0; ni < 4; ++ni) {
        const int col = n0 + wn + ni * 16 + rc;
        const float badd = bias[col];
        if (MODE == 2) {
          const int rowb = m0 + wm + mi * 16 + quad * 4;
          short4v o;
#pragma unroll
          for (int r = 0; r < 4; ++r) o[r] = f2bf_s(acc[mi][ni][r] + badd);
          const size_t idx = (size_t)(rowb >> 11) * (1024u * 2048u) +
                             (size_t)col * 2048u + (size_t)(rowb & 2047);
          *(short4v*)((short*)Cout + idx) = o;
        } else {
#pragma unroll
          for (int r = 0; r < 4; ++r) {
            const int row = m0 + wm + mi * 16 + quad * 4 + r;
            ((__hip_bfloat16*)Cout)[(size_t)row * ldc + col] =
                __float2bfloat16((acc[mi][ni][r] + badd) * qsc);
          }
        }
      }
    }
  }
}

// QKV: flat grid 1536. Group = 8 blocks (fixed y, all 8 x) sharing one A-strip.
__global__ __launch_bounds__(256)
void qkv_fused(const __hip_bfloat16* __restrict__ xb,
               const __hip_bfloat16* __restrict__ Wt,
               __hip_bfloat16* __restrict__ qb, __hip_bfloat16* __restrict__ kb,
               __hip_bfloat16* __restrict__ vt,
               const float* __restrict__ bq, const float* __restrict__ bk,
               const float* __restrict__ bv, const float* __restrict__ tptr) {
  __shared__ __align__(16) __hip_bfloat16 sA[128 * 64];
  __shared__ __align__(16) __hip_bfloat16 sB[128 * 64];
  const int lin = blockIdx.x;
  const int j = lin & 7, t = lin >> 3;
  const int x = t & 7;
  const int G = j + 8 * (t >> 3);
  const int z = G >> 6, y = G & 63;
  const int m0 = y * 128, n0 = x * 128;

  const __hip_bfloat16* B = Wt + (size_t)z * 1024 * 1024;
  if (z == 0)
    gemm_body<1>(xb, B, qb, bq, 1024, 1024, 1024, 1024, sA, sB, m0, n0, tptr);
  else if (z == 1)
    gemm_body<1>(xb, B, kb, bk, 1024, 1024, 1024, 1024, sA, sB, m0, n0, nullptr);
  else
    gemm_body<2>(xb, B, vt, bv, 1024, 1024, 1024, 0, sA, sB, m0, n0, nullptr);
}

// ---------------------------------------------------------------------------
// Scores->P~: 256x128 tile, 512 threads (8 waves, 4m x 2n), BK=64.
// R16-validated: staged 384 MB (-25% vs 128^2 grid 1024), LDS 48KB -> 2/CU.
// MODE-3 epilogue: P~ = bf16(e^acc) + per-(row,chunk64) stats (l,w).
// ---------------------------------------------------------------------------
__global__ __launch_bounds__(512)
void scores_bigm(const __hip_bfloat16* __restrict__ qb,
                 const __hip_bfloat16* __restrict__ kb,
                 __hip_bfloat16* __restrict__ Pt,
                 float* __restrict__ stats) {
  __shared__ __align__(16) __hip_bfloat16 sA[256 * 64];  // 32 KB
  __shared__ __align__(16) __hip_bfloat16 sB[128 * 64];  // 16 KB
  const int lin = blockIdx.x;
  const int G = (lin & 7) * 64 + (lin >> 3);   // bijective: 512 = 8 * 64
  const size_t z = G >> 7;                     // batch (128 tiles each)
  const int rr = G & 127;
  const int y = rr >> 4;                       // 0..7  (256-row tiles)
  const int x = rr & 15;                       // 0..15 (128-col tiles)
  const int m0 = y * 256, n0 = x * 128;
  const __hip_bfloat16* A  = qb + z * 2048 * 1024;
  const __hip_bfloat16* Bt = kb + z * 2048 * 1024;
  __hip_bfloat16* Cout = Pt + z * 2048 * 2048;
  float* st = stats + z * 2048 * 64;

  const int tid  = threadIdx.x;
  const int lane = tid & 63;
  const int wid  = tid >> 6;           // 0..7
  const int wm   = (wid >> 1) * 64;    // 0,64,128,192
  const int wn   = (wid & 1) * 64;     // 0,64
  const int quad = lane >> 4;
  const int rc   = lane & 15;

  f32x4 acc[4][4] = {};

  const int srow = tid >> 3;                          // 0..63
  const int scol = ((tid & 7) ^ ((tid >> 3) & 7)) * 8;
  const __hip_bfloat16* Ag = A  + (size_t)(m0 + srow) * 1024 + scol;
  const __hip_bfloat16* Bg = Bt + (size_t)(n0 + srow) * 1024 + scol;

  for (int k0 = 0; k0 < 1024; k0 += 64) {
#pragma unroll
    for (int p = 0; p < 4; ++p)
      async_load16(Ag + k0 + (size_t)(64 * p) * 1024, &sA[(tid + 512 * p) * 8]);
#pragma unroll
    for (int p = 0; p < 2; ++p)
      async_load16(Bg + k0 + (size_t)(64 * p) * 1024, &sB[(tid + 512 * p) * 8]);
    __syncthreads();

#pragma unroll
    for (int kk = 0; kk < 2; ++kk) {
      const int xo = ((kk * 4 + quad) ^ (rc & 7)) * 8;
      short8 af[4], bf[4];
#pragma unroll
      for (int i = 0; i < 4; ++i)
        af[i] = *(const short8*)&sA[(wm + i * 16 + rc) * 64 + xo];
#pragma unroll
      for (int i = 0; i < 4; ++i)
        bf[i] = *(const short8*)&sB[(wn + i * 16 + rc) * 64 + xo];

#pragma unroll
      for (int mi = 0; mi < 4; ++mi)
#pragma unroll
        for (int ni = 0; ni < 4; ++ni)
          acc[mi][ni] = __builtin_amdgcn_mfma_f32_16x16x32_bf16(
              af[mi], bf[ni], acc[mi][ni], 0, 0, 0);
    }
    __syncthreads();
  }

  const int chunk = (n0 + wn) >> 6;
#pragma unroll
  for (int mi = 0; mi < 4; ++mi) {
    float l_acc[4] = {}, w_acc[4] = {};
#pragma unroll
    for (int ni = 0; ni < 4; ++ni)
#pragma unroll
      for (int r = 0; r < 4; ++r) {
        const float xv = acc[mi][ni][r];   // already /(8*temp): q pre-scaled
        const float e = __expf(xv);
        acc[mi][ni][r] = e;
        l_acc[r] += e;
        w_acc[r] += e * xv;
      }
#pragma unroll
    for (int r = 0; r < 4; ++r) {
      float l = l_acc[r], w = w_acc[r];
#pragma unroll
      for (int off = 1; off < 16; off <<= 1) {
        l += __shfl_xor(l, off);
        w += __shfl_xor(w, off);
      }
      if (rc == 0) {
        const int row = m0 + wm + mi * 16 + quad * 4 + r;
        *(float2*)&st[((size_t)row * 32 + chunk) * 2] = make_float2(l, w);
      }
    }
#pragma unroll
    for (int ni = 0; ni < 4; ++ni) {
      const int col = n0 + wn + ni * 16 + rc;
#pragma unroll
      for (int r = 0; r < 4; ++r) {
        const int row = m0 + wm + mi * 16 + quad * 4 + r;
        Cout[(size_t)row * 2048 + col] = __float2bfloat16(acc[mi][ni][r]);
      }
    }
  }
}

// PV: flat grid 512. Group = 4 blocks (2y x 2x). out scaled by inv_l[row].
__global__ __launch_bounds__(256)
void pv_swz(const __hip_bfloat16* __restrict__ Pt,
            const __hip_bfloat16* __restrict__ vt,
            float* __restrict__ out,
            const float* __restrict__ inv_l) {
  __shared__ __align__(16) __hip_bfloat16 sA[128 * 64];
  __shared__ __align__(16) __hip_bfloat16 sB[128 * 64];
  const int lin = blockIdx.x;
  const int j = lin & 7, t = lin >> 3;
  const int w = t & 3;
  const int G = j + 8 * (t >> 2);
  const size_t z = G >> 5;
  const int r = G & 31;
  const int y = (r >> 2) * 2 + (w >> 1);
  const int x = (r & 3) * 2 + (w & 1);
  gemm_body<4>(Pt + z * 2048 * 2048, vt + z * 1024 * 2048,
               out + z * 2048 * 1024, nullptr, 2048, 2048, 2048, 1024,
               sA, sB, y * 128, x * 128, inv_l + z * 2048);
}

// ---------------------------------------------------------------------------
// Fused prep: blocks [0,4096) cast x->xb (bf16x8); blocks [4096,4864) do the
// three weight transposes (z = (b-4096)>>8, 16x16 tiles of 64x64).
__global__ __launch_bounds__(256)
void prep_fused(const float* __restrict__ x, __hip_bfloat16* __restrict__ xb,
                const float* __restrict__ Wq, const float* __restrict__ Wk,
                const float* __restrict__ Wv, __hip_bfloat16* __restrict__ Wt) {
  if (blockIdx.x < 4096) {
    const int i = (blockIdx.x * 256 + threadIdx.x) * 8;
    const float4 a = *(const float4*)(x + i);
    const float4 b = *(const float4*)(x + i + 4);
    short8 o;
    o[0] = f2bf_s(a.x); o[1] = f2bf_s(a.y); o[2] = f2bf_s(a.z); o[3] = f2bf_s(a.w);
    o[4] = f2bf_s(b.x); o[5] = f2bf_s(b.y); o[6] = f2bf_s(b.z); o[7] = f2bf_s(b.w);
    *(short8*)((short*)xb + i) = o;
  } else {
    __shared__ float tile[64][65];
    const int b = blockIdx.x - 4096;
    const int z = b >> 8;
    const int rem = b & 255;
    const int c0 = (rem & 15) * 64;
    const int r0 = (rem >> 4) * 64;
    const float* src = (z == 0) ? Wq : (z == 1) ? Wk : Wv;
    __hip_bfloat16* dst = Wt + (size_t)z * 1024 * 1024;
    const int lane = threadIdx.x & 63;
    const int grp  = threadIdx.x >> 6;
#pragma unroll
    for (int i = 0; i < 16; ++i) {
      const int r = grp * 16 + i;
      tile[r][lane] = src[(size_t)(r0 + r) * 1024 + c0 + lane];
    }
    __syncthreads();
#pragma unroll
    for (int i = 0; i < 16; ++i) {
      const int r = grp * 16 + i;
      dst[(size_t)(c0 + r) * 1024 + r0 + lane] = __float2bfloat16(tile[lane][r]);
    }
  }
}

// ---------------------------------------------------------------------------
// Per-row stats reduction: row's 32 (l,w) chunk-pairs (256B contiguous) ->
// inv_l[row] = 1/sum(l), Hrow[row] = log(l) - w/l. 8192 rows, 32 blocks.
__global__ __launch_bounds__(256)
void stats_reduce(const float* __restrict__ stats,
                  float* __restrict__ inv_l, float* __restrict__ Hrow) {
  const int row = blockIdx.x * 256 + threadIdx.x;
  const float* sp = stats + (size_t)row * 64;
  float l = 0.f, w = 0.f;
#pragma unroll
  for (int j = 0; j < 16; ++j) {
    const float4 a = *(const float4*)(sp + j * 4);
    l += a.x + a.z;
    w += a.y + a.w;
  }
  const float il = 1.0f / l;
  inv_l[row] = il;
  Hrow[row] = __logf(l) - w * il;
}

// One block: sum Hrow[0..8191], out = mean.
__global__ __launch_bounds__(256)
void reduce_entropy(const float* __restrict__ Hrow, float* __restrict__ out) {
  const int tid  = threadIdx.x;
  const int lane = tid & 63;
  const int wid  = tid >> 6;
  float s = 0.f;
#pragma unroll
  for (int j = 0; j < 8; ++j) {
    const float4 a = *(const float4*)(Hrow + j * 1024 + tid * 4);
    s += a.x + a.y + a.z + a.w;
  }
#pragma unroll
  for (int off = 1; off < 64; off <<= 1) s += __shfl_xor(s, off);
  __shared__ float red[4];
  if (lane == 0) red[wid] = s;
  __syncthreads();
  if (tid == 0)
    out[0] = (red[0] + red[1] + red[2] + red[3]) * (1.0f / 8192.0f);
}

// ---------------------------------------------------------------------------
extern "C" void kernel_launch(void* const* d_in, const int* in_sizes, int n_in,
                              void* d_out, int out_size, void* d_ws, size_t ws_size,
                              hipStream_t stream) {
  const float* x    = (const float*)d_in[0];
  const float* Wq   = (const float*)d_in[1];
  const float* bq   = (const float*)d_in[2];
  const float* Wk   = (const float*)d_in[3];
  const float* bk   = (const float*)d_in[4];
  const float* Wv   = (const float*)d_in[5];
  const float* bv   = (const float*)d_in[6];
  const float* temp = (const float*)d_in[7];
  float* out = (float*)d_out;
  char* ws = (char*)d_ws;

  __hip_bfloat16* qb    = (__hip_bfloat16*)(ws + 0);
  __hip_bfloat16* kb    = (__hip_bfloat16*)(ws + 16777216);
  __hip_bfloat16* vt    = (__hip_bfloat16*)(ws + 33554432);
  __hip_bfloat16* xb    = (__hip_bfloat16*)(ws + 50331648);
  __hip_bfloat16* Wt    = (__hip_bfloat16*)(ws + 67108864);
  __hip_bfloat16* Pt    = (__hip_bfloat16*)(ws + 73400320);
  float*          stats = (float*)(ws + 106954752);
  float*          inv_l = (float*)(ws + 109051904);
  float*          Hrow  = (float*)(ws + 109084672);

  prep_fused<<<4864, 256, 0, stream>>>(x, xb, Wq, Wk, Wv, Wt);

  qkv_fused<<<1536, 256, 0, stream>>>(xb, Wt, qb, kb, vt, bq, bk, bv, temp);

  scores_bigm<<<512, 512, 0, stream>>>(qb, kb, Pt, stats);
  stats_reduce<<<32, 256, 0, stream>>>(stats, inv_l, Hrow);
  pv_swz<<<512, 256, 0, stream>>>(Pt, vt, out, inv_l);

  reduce_entropy<<<1, 256, 0, stream>>>(Hrow, out + 8388608);
}